// Round 3
// baseline (561.183 us; speedup 1.0000x reference)
//
#include <hip/hip_runtime.h>
#include <stdint.h>

#define NE 50000   // entities
#define DD 128     // dim
#define RR 16      // relations
#define EE 50000   // edges per relation
#define NT 128     // node tile per block
#define NTOT (RR * NE)                 // 800000 flat (n,r) keys, node-major
#define SCAN_BLK 4096
#define NSCAN ((NTOT + SCAN_BLK - 1) / SCAN_BLK)   // 196

typedef short  shortx8 __attribute__((ext_vector_type(8)));
typedef short  shortx4 __attribute__((ext_vector_type(4)));
typedef float  floatx4 __attribute__((ext_vector_type(4)));

__device__ __forceinline__ unsigned short f2bf(float f) {
    unsigned u = __float_as_uint(f);
    u += 0x7fffu + ((u >> 16) & 1u);   // RNE
    return (unsigned short)(u >> 16);
}
__device__ __forceinline__ float bf2f(unsigned short h) {
    return __uint_as_float(((unsigned)h) << 16);
}

__device__ __forceinline__ void lds_dma16(const void* g, void* l) {
    __builtin_amdgcn_global_load_lds(
        (const __attribute__((address_space(1))) unsigned int*)g,
        (__attribute__((address_space(3))) unsigned int*)l, 16, 0, 0);
}

// rel_trans fp32 -> bf16, XOR-swizzle pre-applied so layer staging is a linear copy.
// chunk c = r*2048 + row*16 + lc ; dst chunk = (c & ~15) | pc, pc = (lc&8)|((lc^row)&7)
__global__ void cvtT(const float* __restrict__ rt, unsigned short* __restrict__ Tb) {
    int c = blockIdx.x * 256 + threadIdx.x;   // 32768 chunks
    int lc  = c & 15;
    int row = (c >> 4) & 127;
    int pc  = (lc & 8) | ((lc ^ row) & 7);
    const float4* src = (const float4*)(rt + (size_t)c * 8);
    float4 v0 = src[0], v1 = src[1];
    shortx8 w;
    w[0] = (short)f2bf(v0.x); w[1] = (short)f2bf(v0.y);
    w[2] = (short)f2bf(v0.z); w[3] = (short)f2bf(v0.w);
    w[4] = (short)f2bf(v1.x); w[5] = (short)f2bf(v1.y);
    w[6] = (short)f2bf(v1.z); w[7] = (short)f2bf(v1.w);
    *(shortx8*)(Tb + ((size_t)((c & ~15) | pc)) * 8) = w;
}

__global__ void cvtE(const float4* __restrict__ in, shortx4* __restrict__ out, int n4) {
    int i = blockIdx.x * 256 + threadIdx.x;
    if (i < n4) {
        float4 v = in[i];
        shortx4 w;
        w[0] = (short)f2bf(v.x); w[1] = (short)f2bf(v.y);
        w[2] = (short)f2bf(v.z); w[3] = (short)f2bf(v.w);
        out[i] = w;
    }
}

// key = node*RR + r  (node-major). blockIdx.y = relation.
__global__ void hist_k(const int* __restrict__ erow, int* __restrict__ counts) {
    int r  = blockIdx.y;
    int i4 = blockIdx.x * 256 + threadIdx.x;
    if (i4 < EE / 4) {
        int4 rw = *(const int4*)(erow + (size_t)r * EE + i4 * 4);
        atomicAdd(&counts[rw.x * RR + r], 1);
        atomicAdd(&counts[rw.y * RR + r], 1);
        atomicAdd(&counts[rw.z * RR + r], 1);
        atomicAdd(&counts[rw.w * RR + r], 1);
    }
}

// ---- 3-phase flat exclusive scan over counts[NTOT] -> rp[NTOT+1], cursor(=counts)
__global__ void scanA(const int* __restrict__ c, int* __restrict__ bsum) {
    int b = blockIdx.x, t = threadIdx.x;
    int base = b * SCAN_BLK + t * 16;
    int s = 0;
    #pragma unroll
    for (int i = 0; i < 16; i++) {
        int idx = base + i;
        if (idx < NTOT) s += c[idx];
    }
    __shared__ int sh[256];
    sh[t] = s;
    __syncthreads();
    for (int off = 128; off > 0; off >>= 1) {
        if (t < off) sh[t] += sh[t + off];
        __syncthreads();
    }
    if (t == 0) bsum[b] = sh[0];
}

__global__ void scanB(int* __restrict__ bsum) {
    int t = threadIdx.x;
    int v = (t < NSCAN) ? bsum[t] : 0;
    __shared__ int sh[256];
    sh[t] = v;
    __syncthreads();
    for (int off = 1; off < 256; off <<= 1) {
        int add = (t >= off) ? sh[t - off] : 0;
        __syncthreads();
        sh[t] += add;
        __syncthreads();
    }
    if (t < NSCAN) bsum[t] = sh[t] - v;   // exclusive
}

__global__ void scanC(int* __restrict__ counts, int* __restrict__ rp,
                      const int* __restrict__ bsum) {
    int b = blockIdx.x, t = threadIdx.x;
    int base = b * SCAN_BLK + t * 16;
    int vals[16];
    int s = 0;
    #pragma unroll
    for (int i = 0; i < 16; i++) {
        int idx = base + i;
        vals[i] = (idx < NTOT) ? counts[idx] : 0;
        s += vals[i];
    }
    __shared__ int sh[256];
    sh[t] = s;
    __syncthreads();
    for (int off = 1; off < 256; off <<= 1) {
        int add = (t >= off) ? sh[t - off] : 0;
        __syncthreads();
        sh[t] += add;
        __syncthreads();
    }
    int run = bsum[b] + sh[t] - s;
    #pragma unroll
    for (int i = 0; i < 16; i++) {
        int idx = base + i;
        if (idx < NTOT) {
            int cv = vals[i];
            rp[idx]     = run;
            counts[idx] = run;   // cursor for fill_k
            run += cv;
            if (idx == NTOT - 1) rp[NTOT] = run;
        }
    }
}

__global__ void fill_k(const int* __restrict__ erow, const int* __restrict__ ecol,
                       const float* __restrict__ eval, int* __restrict__ cursor,
                       int2* __restrict__ edges) {
    int r  = blockIdx.y;
    int i4 = blockIdx.x * 256 + threadIdx.x;
    if (i4 < EE / 4) {
        int4   rw = *(const int4*)(erow + (size_t)r * EE + i4 * 4);
        int4   cl = *(const int4*)(ecol + (size_t)r * EE + i4 * 4);
        float4 vl = *(const float4*)(eval + (size_t)r * EE + i4 * 4);
        int p;
        p = atomicAdd(&cursor[rw.x * RR + r], 1); edges[p] = make_int2(cl.x, __float_as_int(vl.x));
        p = atomicAdd(&cursor[rw.y * RR + r], 1); edges[p] = make_int2(cl.y, __float_as_int(vl.y));
        p = atomicAdd(&cursor[rw.z * RR + r], 1); edges[p] = make_int2(cl.z, __float_as_int(vl.z));
        p = atomicAdd(&cursor[rw.w * RR + r], 1); edges[p] = make_int2(cl.w, __float_as_int(vl.w));
    }
}

__device__ __forceinline__ void accum_chunks(float a0[8], float a1[8], float v,
                                             shortx8 c0, shortx8 c1) {
    #pragma unroll
    for (int j = 0; j < 8; j++) {
        a0[j] = fmaf(v, bf2f((unsigned short)c0[j]), a0[j]);
        a1[j] = fmaf(v, bf2f((unsigned short)c1[j]), a1[j]);
    }
}

__device__ __forceinline__ void tail_edges(const int2* __restrict__ eg,
                                           const unsigned short* __restrict__ embIn,
                                           int dgrp, int s, int c,
                                           float a0[8], float a1[8]) {
    #pragma unroll 1
    for (int k = s + 2; k < s + c; k++) {   // rare: deg >= 3
        int2 E = eg[k];
        float v = __int_as_float(E.y);
        const unsigned short* rw_ = embIn + (size_t)E.x * DD;
        shortx8 t0 = *(const shortx8*)(rw_ + dgrp * 8);
        shortx8 t1 = *(const shortx8*)(rw_ + dgrp * 8 + 64);
        accum_chunks(a0, a1, v, t0, t1);
    }
}

// Fused layer, software-pipelined:
//   per relation interval: [write Bt(r); DMA At(r)] | barrier | issue emb(r+1), rp(r+2),
//   MFMA(r), edges(r+2), consume emb(r+1)->wreg | barrier
template<bool FINAL>
__global__ __launch_bounds__(512, 4)
void layer_k(const unsigned short* __restrict__ embIn,
             const unsigned short* __restrict__ Tb,
             const int* __restrict__ rp,
             const int2* __restrict__ eg,
             unsigned short* __restrict__ embOut,
             float* __restrict__ outF)
{
    __shared__ __align__(16) unsigned short At[128 * 128];
    __shared__ __align__(16) unsigned short Bt[128 * 128];
    __shared__ float ssred[4][128];

    const int t    = threadIdx.x;
    const int lane = t & 63;
    const int w    = t >> 6;
    const int wi   = w >> 1;      // i block (x32)
    const int wn   = w & 1;       // n block (x64)
    const int colq = lane & 15;
    const int q    = lane >> 4;
    const int n0   = blockIdx.x * NT;
    const int nsub = t >> 3;      // node within pass (0..63)
    const int dgrp = t & 7;       // dim chunks dgrp, dgrp+8

    const int nn[2] = { n0 + nsub, n0 + 64 + nsub };

    floatx4 acc[2][4];
    #pragma unroll
    for (int a = 0; a < 2; a++)
        #pragma unroll
        for (int c = 0; c < 4; c++)
            acc[a][c] = (floatx4){0.f, 0.f, 0.f, 0.f};

    auto loadRange = [&](int r, int p, int& s, int& c) {
        int n = nn[p];
        if (n < NE) { int key = n * RR + r; int a = rp[key]; int b = rp[key + 1]; s = a; c = b - a; }
        else        { s = 0; c = 0; }
    };

    shortx8 wreg[4];     // packed gathered B for current relation: [p*2 + chunk]

    // ---- prologue: gather relation 0 (exposed latency, once)
    {
        int sP[2], cP[2];
        #pragma unroll
        for (int p = 0; p < 2; p++) loadRange(0, p, sP[p], cP[p]);
        int2 P0[2], P1[2];
        #pragma unroll
        for (int p = 0; p < 2; p++) {
            P0[p] = make_int2(0, 0); P1[p] = make_int2(0, 0);
            if (cP[p] > 0) P0[p] = eg[sP[p]];
            if (cP[p] > 1) P1[p] = eg[sP[p] + 1];
        }
        #pragma unroll
        for (int p = 0; p < 2; p++) {
            float a0[8], a1[8];
            #pragma unroll
            for (int j = 0; j < 8; j++) { a0[j] = 0.f; a1[j] = 0.f; }
            if (cP[p] > 0) {
                const unsigned short* rw_ = embIn + (size_t)P0[p].x * DD;
                accum_chunks(a0, a1, __int_as_float(P0[p].y),
                             *(const shortx8*)(rw_ + dgrp * 8),
                             *(const shortx8*)(rw_ + dgrp * 8 + 64));
            }
            if (cP[p] > 1) {
                const unsigned short* rw_ = embIn + (size_t)P1[p].x * DD;
                accum_chunks(a0, a1, __int_as_float(P1[p].y),
                             *(const shortx8*)(rw_ + dgrp * 8),
                             *(const shortx8*)(rw_ + dgrp * 8 + 64));
            }
            tail_edges(eg, embIn, dgrp, sP[p], cP[p], a0, a1);
            #pragma unroll
            for (int j = 0; j < 8; j++) {
                wreg[p * 2 + 0][j] = (short)f2bf(a0[j]);
                wreg[p * 2 + 1][j] = (short)f2bf(a1[j]);
            }
        }
    }
    // edge state for relation 1
    int  sN[2], cN[2];
    int2 F0[2], F1[2];
    #pragma unroll
    for (int p = 0; p < 2; p++) {
        loadRange(1, p, sN[p], cN[p]);
        F0[p] = make_int2(0, 0); F1[p] = make_int2(0, 0);
        if (cN[p] > 0) F0[p] = eg[sN[p]];
        if (cN[p] > 1) F1[p] = eg[sN[p] + 1];
    }

    #pragma unroll 1
    for (int r = 0; r < RR; r++) {
        // ---- 1. At DMA (async) + Bt writes for relation r
        {
            const unsigned short* src = Tb + (size_t)r * (DD * DD);
            #pragma unroll
            for (int it = 0; it < 4; it++) {
                int g = it * 512 + t;
                lds_dma16(src + (size_t)g * 8, &At[g * 8]);
            }
        }
        #pragma unroll
        for (int p = 0; p < 2; p++) {
            int nl  = p * 64 + nsub;
            int pcA = (dgrp ^ nl) & 7;
            int pcB = 8 | pcA;
            *(shortx8*)&Bt[nl * 128 + pcA * 8] = wreg[p * 2 + 0];
            *(shortx8*)&Bt[nl * 128 + pcB * 8] = wreg[p * 2 + 1];
        }
        __syncthreads();   // drains At DMA (vmcnt), Bt writes visible

        // ---- 2. issue emb loads for relation r+1
        shortx8 eb[2][2][2];   // [p][edge][chunk]
        float   v0f[2], v1f[2];
        if (r + 1 < RR) {
            #pragma unroll
            for (int p = 0; p < 2; p++) {
                v0f[p] = __int_as_float(F0[p].y);
                v1f[p] = __int_as_float(F1[p].y);
                if (cN[p] > 0) {
                    const unsigned short* rw_ = embIn + (size_t)F0[p].x * DD;
                    eb[p][0][0] = *(const shortx8*)(rw_ + dgrp * 8);
                    eb[p][0][1] = *(const shortx8*)(rw_ + dgrp * 8 + 64);
                }
                if (cN[p] > 1) {
                    const unsigned short* rw_ = embIn + (size_t)F1[p].x * DD;
                    eb[p][1][0] = *(const shortx8*)(rw_ + dgrp * 8);
                    eb[p][1][1] = *(const shortx8*)(rw_ + dgrp * 8 + 64);
                }
            }
        }
        // ---- 3. rp loads for relation r+2
        int s2[2], c2[2];
        s2[0] = s2[1] = 0; c2[0] = c2[1] = 0;
        if (r + 2 < RR) {
            #pragma unroll
            for (int p = 0; p < 2; p++) loadRange(r + 2, p, s2[p], c2[p]);
        }

        // ---- 4. MFMA(r)
        #pragma unroll
        for (int kt = 0; kt < 4; kt++) {
            int lc = kt * 4 + q;
            shortx8 af[2], bfr[4];
            #pragma unroll
            for (int it2 = 0; it2 < 2; it2++) {
                int row = wi * 32 + it2 * 16 + colq;
                int pc  = (lc & 8) | ((lc ^ row) & 7);
                af[it2] = *(const shortx8*)&At[row * 128 + pc * 8];
            }
            #pragma unroll
            for (int c = 0; c < 4; c++) {
                int nl = wn * 64 + c * 16 + colq;
                int pc = (lc & 8) | ((lc ^ nl) & 7);
                bfr[c] = *(const shortx8*)&Bt[nl * 128 + pc * 8];
            }
            #pragma unroll
            for (int it2 = 0; it2 < 2; it2++)
                #pragma unroll
                for (int c = 0; c < 4; c++)
                    acc[it2][c] = __builtin_amdgcn_mfma_f32_16x16x32_bf16(af[it2], bfr[c], acc[it2][c], 0, 0, 0);
        }

        // ---- 5. edge entries for relation r+2
        int2 G0[2], G1[2];
        #pragma unroll
        for (int p = 0; p < 2; p++) { G0[p] = make_int2(0, 0); G1[p] = make_int2(0, 0); }
        if (r + 2 < RR) {
            #pragma unroll
            for (int p = 0; p < 2; p++) {
                if (c2[p] > 0) G0[p] = eg[s2[p]];
                if (c2[p] > 1) G1[p] = eg[s2[p] + 1];
            }
        }

        // ---- 6. consume emb(r+1): FMA + tail + pack -> wreg
        if (r + 1 < RR) {
            #pragma unroll
            for (int p = 0; p < 2; p++) {
                float a0[8], a1[8];
                #pragma unroll
                for (int j = 0; j < 8; j++) { a0[j] = 0.f; a1[j] = 0.f; }
                if (cN[p] > 0) accum_chunks(a0, a1, v0f[p], eb[p][0][0], eb[p][0][1]);
                if (cN[p] > 1) accum_chunks(a0, a1, v1f[p], eb[p][1][0], eb[p][1][1]);
                tail_edges(eg, embIn, dgrp, sN[p], cN[p], a0, a1);
                #pragma unroll
                for (int j = 0; j < 8; j++) {
                    wreg[p * 2 + 0][j] = (short)f2bf(a0[j]);
                    wreg[p * 2 + 1][j] = (short)f2bf(a1[j]);
                }
            }
        }
        // ---- 7. shift pipeline state
        #pragma unroll
        for (int p = 0; p < 2; p++) { sN[p] = s2[p]; cN[p] = c2[p]; F0[p] = G0[p]; F1[p] = G1[p]; }
        __syncthreads();
    }

    // ---- epilogue. D: col = lane&15 -> n, row = q*4+reg -> i (within wave tile)
    if (!FINAL) {
        #pragma unroll
        for (int c = 0; c < 4; c++) {
            int n = n0 + wn * 64 + c * 16 + colq;
            if (n < NE) {
                #pragma unroll
                for (int it2 = 0; it2 < 2; it2++) {
                    shortx4 wv;
                    #pragma unroll
                    for (int g = 0; g < 4; g++) {
                        float v = acc[it2][c][g];
                        v = v > 0.f ? v : 0.f;
                        wv[g] = (short)f2bf(v);
                    }
                    *(shortx4*)(embOut + ((size_t)n * DD + wi * 32 + it2 * 16 + q * 4)) = wv;
                }
            }
        }
    } else {
        float ssc[4];
        #pragma unroll
        for (int c = 0; c < 4; c++) {
            float ss = 0.f;
            #pragma unroll
            for (int it2 = 0; it2 < 2; it2++)
                #pragma unroll
                for (int g = 0; g < 4; g++) {
                    float v = acc[it2][c][g];
                    v = v > 0.f ? v : 0.f;
                    acc[it2][c][g] = v;
                    ss += v * v;
                }
            ss += __shfl_xor(ss, 16, 64);   // reduce over q quads
            ss += __shfl_xor(ss, 32, 64);
            ssc[c] = ss;
        }
        if (q == 0) {
            #pragma unroll
            for (int c = 0; c < 4; c++)
                ssred[wi][wn * 64 + c * 16 + colq] = ssc[c];
        }
        __syncthreads();
        #pragma unroll
        for (int c = 0; c < 4; c++) {
            int nl = wn * 64 + c * 16 + colq;
            float tot = ssred[0][nl] + ssred[1][nl] + ssred[2][nl] + ssred[3][nl];
            float scale = 1.f / fmaxf(sqrtf(tot), 1e-12f);
            int n = n0 + nl;
            if (n < NE) {
                #pragma unroll
                for (int it2 = 0; it2 < 2; it2++) {
                    floatx4 v4;
                    #pragma unroll
                    for (int g = 0; g < 4; g++) v4[g] = acc[it2][c][g] * scale;
                    *(floatx4*)(outF + ((size_t)n * DD + wi * 32 + it2 * 16 + q * 4)) = v4;
                }
            }
        }
    }
}

static inline size_t align256(size_t x) { return (x + 255) & ~(size_t)255; }

extern "C" void kernel_launch(void* const* d_in, const int* in_sizes, int n_in,
                              void* d_out, int out_size, void* d_ws, size_t ws_size,
                              hipStream_t stream)
{
    const float* ent_emb   = (const float*)d_in[0];   // [NE, DD] fp32
    const float* rel_trans = (const float*)d_in[1];   // [RR, DD, DD] fp32
    const float* edge_val  = (const float*)d_in[2];   // [RR, EE] fp32
    const int*   edge_row  = (const int*)d_in[3];     // [RR, EE] int32
    const int*   edge_col  = (const int*)d_in[4];     // [RR, EE] int32
    float* out = (float*)d_out;                       // [NE, DD] fp32

    char* ws = (char*)d_ws;
    size_t off = 0;
    int* counts = (int*)(ws + off);  off = align256(off + (size_t)NTOT * 4);        // hist -> cursor
    int* rpf    = (int*)(ws + off);  off = align256(off + ((size_t)NTOT + 1) * 4);  // node-major row_ptr
    int* bsum   = (int*)(ws + off);  off = align256(off + 256 * 4);
    int2* edges = (int2*)(ws + off); off = align256(off + (size_t)NTOT * 8);        // node-major (col,val)
    unsigned short* Tb   = (unsigned short*)(ws + off); off = align256(off + (size_t)RR * DD * DD * 2);
    unsigned short* embA = (unsigned short*)(ws + off); off = align256(off + (size_t)NE * DD * 2);
    unsigned short* embB = (unsigned short*)(ws + off); off = align256(off + (size_t)NE * DD * 2);
    // total ~39 MB

    hipMemsetAsync(counts, 0, (size_t)NTOT * 4, stream);
    cvtT<<<(RR * DD * DD / 8) / 256, 256, 0, stream>>>(rel_trans, Tb);   // 128 blocks
    cvtE<<<((NE * DD / 4) + 255) / 256, 256, 0, stream>>>(
        (const float4*)ent_emb, (shortx4*)embA, NE * DD / 4);
    dim3 eg_grid((EE / 4 + 255) / 256, RR);
    hist_k<<<eg_grid, 256, 0, stream>>>(edge_row, counts);
    scanA<<<NSCAN, 256, 0, stream>>>(counts, bsum);
    scanB<<<1, 256, 0, stream>>>(bsum);
    scanC<<<NSCAN, 256, 0, stream>>>(counts, rpf, bsum);
    fill_k<<<eg_grid, 256, 0, stream>>>(edge_row, edge_col, edge_val, counts, edges);

    int nb = (NE + NT - 1) / NT;  // 391
    layer_k<false><<<nb, 512, 0, stream>>>(embA, Tb, rpf, edges, embB, nullptr);
    layer_k<true ><<<nb, 512, 0, stream>>>(embB, Tb, rpf, edges, nullptr, out);
}